// Round 6
// baseline (90.897 us; speedup 1.0000x reference)
//
#include <hip/hip_runtime.h>
#include <hip/hip_fp16.h>
#include <cmath>

#define BB 4
#define HH 64
#define WW 64
// half-row blocks: 512 blocks x 512 threads, 32 px each
#define COLS2 33
#define NSTR  99                    // SLOT n-stride in words (99 mod 32 = 3 -> conflict-free)
#define SLOT  0                     // 52*99 = 5148 w : {x,y,score} -> packed taps; later pc out
#define SPB   5148                  // 32 w : sparsity channel
#define TAb   5180                  // 64*33 = 2112 w : activations / agg / h1
#define POOL  7292                  // 29168 B

// ---------------- NCHW -> NHWC fp16 transpose (LDS tiled) ----------------
__global__ __launch_bounds__(256) void transpose_half(const float* __restrict__ x,
                                                      __half* __restrict__ xth) {
    int bid = blockIdx.x;
    int b = bid >> 6, y = bid & 63;
    __shared__ float tile[64][65];
    const float* xp = x + ((size_t)b * 64 * HH + y) * WW;
    #pragma unroll
    for (int k = 0; k < 16; ++k) {
        int idx = threadIdx.x + (k << 8);
        int c = idx >> 6, w = idx & 63;
        tile[c][w] = xp[(size_t)c * HH * WW + w];
    }
    __syncthreads();
    __half* op = xth + ((size_t)(b * HH + y) * WW) * 64;
    #pragma unroll
    for (int k = 0; k < 16; ++k) {
        int idx = threadIdx.x + (k << 8);
        int w = idx >> 6, c = idx & 63;
        op[(size_t)w * 64 + c] = __float2half(tile[c][w]);
    }
}

// pointwise rows: lane=(pxl 0..31, grp 0..1); wave covers rows rbase..rbase+RPW-1 per group
template<int RPW>
__device__ inline void pw_acc(const float* __restrict__ P, int pxl, int rbase, int R,
                              const float* __restrict__ W, const float* __restrict__ Bv,
                              float* acc) {
    int oc[RPW];
    #pragma unroll
    for (int r = 0; r < RPW; ++r) {
        oc[r] = min(rbase + r, R - 1);
        acc[r] = Bv[oc[r]];
    }
    #pragma unroll 8
    for (int k = 0; k < 64; ++k) {
        float v = P[TAb + k * COLS2 + pxl];
        #pragma unroll
        for (int r = 0; r < RPW; ++r)
            acc[r] = fmaf(W[oc[r] * 64 + k], v, acc[r]);
    }
}

// ---------------- fused main: 1 block (8 waves, 512 thr) per HALF image row ----------------
__global__ __launch_bounds__(512, 4) void crossd_main(
    const __half* __restrict__ xth, const float* __restrict__ x,
    const float* __restrict__ p_n,
    const float* __restrict__ dwf_w, const float* __restrict__ dwf_b,
    const float* __restrict__ pwf_w, const float* __restrict__ pwf_b,
    const float* __restrict__ dwc_w, const float* __restrict__ dwc_b,
    const float* __restrict__ pwc_w, const float* __restrict__ pwc_b,
    const float* __restrict__ dwm_w, const float* __restrict__ dwm_b,
    const float* __restrict__ pwm_w, const float* __restrict__ pwm_b,
    const float* __restrict__ pc_w, const float* __restrict__ pc_b,
    const float* __restrict__ w1, const float* __restrict__ b1,
    const float* __restrict__ w2, const float* __restrict__ b2,
    float* __restrict__ out)
{
    __shared__ float P[POOL];
    uint32_t* PSu = reinterpret_cast<uint32_t*>(P);
    const int tid  = threadIdx.x;
    const int lane = tid & 63;
    const int wv   = __builtin_amdgcn_readfirstlane(tid >> 6);   // 0..7
    const int pxl  = lane & 31;          // pixel within half-row
    const int grp  = lane >> 5;          // row group 0/1
    const int bid = blockIdx.x;          // 512 blocks
    const int xh = bid & 1, y = (bid >> 1) & 63, b = bid >> 7;
    const __half* xb = xth + (size_t)b * (HH * WW * 64);

    // ---- fused depthwise 3x3 (fp16 input, 3 branches share loads); wave=4 px, lane=ch ----
    float tc_r[4], tm_r[4];
    {
        const int c = lane;
        float wf9[9], wc9[9], wm9[9];
        #pragma unroll
        for (int k9 = 0; k9 < 9; ++k9) {
            wf9[k9] = dwf_w[c * 9 + k9];
            wc9[k9] = dwc_w[c * 9 + k9];
            wm9[k9] = dwm_w[c * 9 + k9];
        }
        const float bf = dwf_b[c], bc = dwc_b[c], bm = dwm_b[c];
        #pragma unroll
        for (int i = 0; i < 4; ++i) {
            const int pxg = xh * 32 + wv * 4 + i;
            float af = bf, ac = bc, am = bm;
            #pragma unroll
            for (int dy = 0; dy < 3; ++dy) {
                int yy = y + dy - 1;
                if (yy < 0 || yy >= HH) continue;
                #pragma unroll
                for (int dx = 0; dx < 3; ++dx) {
                    int xx = pxg + dx - 1;
                    if (xx < 0 || xx >= WW) continue;
                    float v = __half2float(xb[(size_t)((yy << 6) + xx) * 64 + c]);
                    int k = dy * 3 + dx;
                    af = fmaf(v, wf9[k], af);
                    ac = fmaf(v, wc9[k], ac);
                    am = fmaf(v, wm9[k], am);
                }
            }
            P[TAb + c * COLS2 + (wv * 4 + i)] = af;
            tc_r[i] = ac; tm_r[i] = am;
        }
    }
    __syncthreads();

    // ---- f-branch pointwise (32 rows -> x of taps 0..31) ----
    {
        float acc[2];
        pw_acc<2>(P, pxl, (wv * 2 + grp) * 2, 32, pwf_w, pwf_b, acc);
        __syncthreads();                 // TA reads done before t_c overwrite
        #pragma unroll
        for (int r = 0; r < 2; ++r) {
            int o = (wv * 2 + grp) * 2 + r;
            P[SLOT + o * NSTR + pxl * 3] = acc[r];
        }
        #pragma unroll
        for (int i = 0; i < 4; ++i) P[TAb + lane * COLS2 + wv * 4 + i] = tc_r[i];
    }
    __syncthreads();

    // ---- c-branch pointwise (72 rows -> x of taps 32..51, y of taps 0..51) ----
    {
        float acc[5];
        pw_acc<5>(P, pxl, (wv * 2 + grp) * 5, 72, pwc_w, pwc_b, acc);
        __syncthreads();                 // TA reads done before t_m overwrite
        #pragma unroll
        for (int r = 0; r < 5; ++r) {
            int rr = (wv * 2 + grp) * 5 + r;
            if (rr < 72) {
                int og = 32 + rr;
                int e = (og < 52) ? og * NSTR + pxl * 3
                                  : (og - 52) * NSTR + pxl * 3 + 1;
                P[SLOT + e] = acc[r];
            }
        }
        #pragma unroll
        for (int i = 0; i < 4; ++i) P[TAb + lane * COLS2 + wv * 4 + i] = tm_r[i];
    }
    __syncthreads();

    // ---- m-branch pointwise (53 rows -> scores, sparsity) ----
    {
        float acc[4];
        pw_acc<4>(P, pxl, (wv * 2 + grp) * 4, 53, pwm_w, pwm_b, acc);
        #pragma unroll
        for (int r = 0; r < 4; ++r) {
            int o = (wv * 2 + grp) * 4 + r;
            if (o < 52)       P[SLOT + o * NSTR + pxl * 3 + 2] = acc[r];
            else if (o == 52) P[SPB + pxl] = acc[r];
        }
    }
    __syncthreads();

    // ---- gated softmax over 52 scores: lane = n, wave owns 4 px ----
    #pragma unroll
    for (int i = 0; i < 4; ++i) {
        const int px = wv * 4 + i;
        const float sp = P[SPB + px];
        float z = -1e30f;
        if (lane < 52) {
            float s  = P[SLOT + lane * NSTR + px * 3 + 2];
            float sg = 1.0f / (1.0f + __expf(-(s - sp) * 10.0f));
            z = s + __logf(sg + 1e-10f);
        }
        float mx = z;
        #pragma unroll
        for (int d = 32; d >= 1; d >>= 1) mx = fmaxf(mx, __shfl_xor(mx, d));
        float e = (lane < 52) ? __expf(z - mx) : 0.0f;
        float sm = e;
        #pragma unroll
        for (int d = 32; d >= 1; d >>= 1) sm += __shfl_xor(sm, d);
        if (lane < 52) P[SLOT + lane * NSTR + px * 3 + 2] = e / sm;
    }
    __syncthreads();

    // ---- coord-pack: in-place SLOT rewrite, one (n, px) per thread ----
    {
        const int ppx = tid & 31;
        const float fx = (float)(xh * 32 + ppx);
        for (int n = tid >> 5; n < 52; n += 16) {
            const int e = SLOT + n * NSTR + ppx * 3;
            float sx = fx       + p_n[n]      + P[e];
            float sy = (float)y + p_n[52 + n] + P[e + 1];
            float mo = P[e + 2];
            float x0f = floorf(sx), y0f = floorf(sy);
            float wx1 = sx - x0f, wy1 = sy - y0f;
            float wx0 = 1.0f - wx1, wy0 = 1.0f - wy1;
            int x0 = (int)x0f, y0 = (int)y0f;
            int xi0 = min(max(x0, 0), 63), xi1 = min(max(x0 + 1, 0), 63);
            int yi0 = min(max(y0, 0), 63), yi1 = min(max(y0 + 1, 0), 63);
            bool vx0 = (x0 >= 0)  & (x0 <= 63);
            bool vx1 = (x0 >= -1) & (x0 <= 62);
            bool vy0 = (y0 >= 0)  & (y0 <= 63);
            bool vy1 = (y0 >= -1) & (y0 <= 62);
            float m00 = (vy0 & vx0) ? mo * wy0 * wx0 : 0.0f;
            float m01 = (vy0 & vx1) ? mo * wy0 * wx1 : 0.0f;
            float m10 = (vy1 & vx0) ? mo * wy1 * wx0 : 0.0f;
            float m11 = (vy1 & vx1) ? mo * wy1 * wx1 : 0.0f;
            uint32_t a00 = (uint32_t)((yi0 << 6) | xi0);
            uint32_t a11 = (uint32_t)((yi1 << 6) | xi1);
            __half2 hA = __floats2half2_rn(m00, m01);
            __half2 hB = __floats2half2_rn(m10, m11);
            PSu[e]     = a00 | (a11 << 16);
            PSu[e + 1] = *reinterpret_cast<uint32_t*>(&hA);
            PSu[e + 2] = *reinterpret_cast<uint32_t*>(&hB);
        }
    }
    __syncthreads();

    // ---- 52-tap gather (fp16, dwordx2), zero interior barriers ----
    {
        const int sub = lane >> 4;      // 0..3
        const int c4  = lane & 15;      // channel quad
        const int spx = wv * 4 + sub;
        const uint2* xt2 = reinterpret_cast<const uint2*>(xb);
        float4 agg = make_float4(0.f, 0.f, 0.f, 0.f);
        #pragma unroll 4
        for (int n = 0; n < 52; ++n) {
            const int e = SLOT + n * NSTR + spx * 3;
            uint32_t w0 = PSu[e], wA = PSu[e + 1], wB = PSu[e + 2];
            uint32_t a00 = w0 & 0xFFFFu, a11 = w0 >> 16;
            uint32_t a01 = (a00 & ~63u) | (a11 & 63u);
            uint32_t a10 = (a11 & ~63u) | (a00 & 63u);
            __half2 hA = *reinterpret_cast<__half2*>(&wA);
            __half2 hB = *reinterpret_cast<__half2*>(&wB);
            float m00 = __low2float(hA), m01 = __high2float(hA);
            float m10 = __low2float(hB), m11 = __high2float(hB);
            uint2 u00 = xt2[(a00 << 4) + c4];
            uint2 u01 = xt2[(a01 << 4) + c4];
            uint2 u10 = xt2[(a10 << 4) + c4];
            uint2 u11 = xt2[(a11 << 4) + c4];
            #define ACC4(u, m) { \
                __half2 hlo = *reinterpret_cast<__half2*>(&u.x); \
                __half2 hhi = *reinterpret_cast<__half2*>(&u.y); \
                float2 flo = __half22float2(hlo), fhi = __half22float2(hhi); \
                agg.x = fmaf(m, flo.x, agg.x); agg.y = fmaf(m, flo.y, agg.y); \
                agg.z = fmaf(m, fhi.x, agg.z); agg.w = fmaf(m, fhi.y, agg.w); }
            ACC4(u00, m00); ACC4(u01, m01); ACC4(u10, m10); ACC4(u11, m11);
            #undef ACC4
        }
        // store agg transposed [c][px] into TAb (t_m consumed at m-branch barrier)
        P[TAb + (c4 * 4 + 0) * COLS2 + spx] = agg.x;
        P[TAb + (c4 * 4 + 1) * COLS2 + spx] = agg.y;
        P[TAb + (c4 * 4 + 2) * COLS2 + spx] = agg.z;
        P[TAb + (c4 * 4 + 3) * COLS2 + spx] = agg.w;
    }
    __syncthreads();

    // ---- pc 1x1: TAb -> SLOT (dead after gather) ----
    {
        float acc[4];
        pw_acc<4>(P, pxl, (wv * 2 + grp) * 4, 64, pc_w, pc_b, acc);
        __syncthreads();    // SLOT gather-reads + TAb reads complete
        #pragma unroll
        for (int r = 0; r < 4; ++r)
            P[SLOT + ((wv * 2 + grp) * 4 + r) * COLS2 + pxl] = acc[r];
    }
    __syncthreads();

    // ---- mlp1 (relu): SLOT -> TAb ----
    {
        const int rb = (wv * 2 + grp) * 4;
        float acc[4];
        #pragma unroll
        for (int r = 0; r < 4; ++r) acc[r] = b1[rb + r];
        #pragma unroll 8
        for (int k = 0; k < 64; ++k) {
            float v = P[SLOT + k * COLS2 + pxl];
            #pragma unroll
            for (int r = 0; r < 4; ++r) acc[r] = fmaf(w1[(rb + r) * 64 + k], v, acc[r]);
        }
        #pragma unroll
        for (int r = 0; r < 4; ++r) P[TAb + (rb + r) * COLS2 + pxl] = fmaxf(acc[r], 0.0f);
    }
    __syncthreads();

    // ---- mlp2 + residual + store ----
    {
        const int rb = (wv * 2 + grp) * 4;
        float acc[4];
        #pragma unroll
        for (int r = 0; r < 4; ++r) acc[r] = b2[rb + r];
        #pragma unroll 8
        for (int k = 0; k < 64; ++k) {
            float v = P[TAb + k * COLS2 + pxl];
            #pragma unroll
            for (int r = 0; r < 4; ++r) acc[r] = fmaf(w2[(rb + r) * 64 + k], v, acc[r]);
        }
        #pragma unroll
        for (int r = 0; r < 4; ++r) {
            int o = rb + r;
            size_t idx = (((size_t)b * 64 + o) * 64 + y) * 64 + (xh * 32 + pxl);
            out[idx] = acc[r] + x[idx];
        }
    }
}

extern "C" void kernel_launch(void* const* d_in, const int* in_sizes, int n_in,
                              void* d_out, int out_size, void* d_ws, size_t ws_size,
                              hipStream_t stream) {
    const float* x     = (const float*)d_in[0];
    const float* p_n   = (const float*)d_in[1];
    const float* dwf_w = (const float*)d_in[2];
    const float* dwf_b = (const float*)d_in[3];
    const float* pwf_w = (const float*)d_in[4];
    const float* pwf_b = (const float*)d_in[5];
    const float* dwc_w = (const float*)d_in[6];
    const float* dwc_b = (const float*)d_in[7];
    const float* pwc_w = (const float*)d_in[8];
    const float* pwc_b = (const float*)d_in[9];
    const float* dwm_w = (const float*)d_in[10];
    const float* dwm_b = (const float*)d_in[11];
    const float* pwm_w = (const float*)d_in[12];
    const float* pwm_b = (const float*)d_in[13];
    const float* pc_w  = (const float*)d_in[14];
    const float* pc_b  = (const float*)d_in[15];
    const float* w1    = (const float*)d_in[16];
    const float* b1    = (const float*)d_in[17];
    const float* w2    = (const float*)d_in[18];
    const float* b2    = (const float*)d_in[19];

    __half* xth = (__half*)d_ws;      // 2 MB NHWC fp16 copy of x
    float* outp = (float*)d_out;

    hipLaunchKernelGGL(transpose_half, dim3(BB * HH), dim3(256), 0, stream, x, xth);
    hipLaunchKernelGGL(crossd_main, dim3(BB * HH * 2), dim3(512), 0, stream,
                       xth, x, p_n,
                       dwf_w, dwf_b, pwf_w, pwf_b,
                       dwc_w, dwc_b, pwc_w, pwc_b,
                       dwm_w, dwm_b, pwm_w, pwm_b,
                       pc_w, pc_b, w1, b1, w2, b2, outp);
}

// Round 7
// 64.816 us; speedup vs baseline: 1.4024x; 1.4024x over previous
//
#include <hip/hip_runtime.h>
#include <hip/hip_fp16.h>
#include <cmath>

#define BB 4
#define HH 64
#define WW 64
// ---- LDS pool word-offsets (fp32 words), total 31264 w = 122.1 KiB ----
#define WINW  0         // 5*64*64 half  = 10240 w : 5-row fp16 sample window
#define SLOTW 10240     // 52*64 * 4 w   = 13312 w : {ox,oy,-,-} -> packed taps; later pc out
#define SBW   23552     // 53*67         =  3551 w : scores -> mod (stride 67, conflict-free)
#define TAW   27103     // 64*65         =  4160 w : activations / agg / h1
#define POOLW 31264

// ---------------- NCHW -> NHWC fp16 transpose (LDS tiled) ----------------
__global__ __launch_bounds__(256) void transpose_half(const float* __restrict__ x,
                                                      __half* __restrict__ xth) {
    int bid = blockIdx.x;
    int b = bid >> 6, y = bid & 63;
    __shared__ float tile[64][65];
    const float* xp = x + ((size_t)b * 64 * HH + y) * WW;
    #pragma unroll
    for (int k = 0; k < 16; ++k) {
        int idx = threadIdx.x + (k << 8);
        int c = idx >> 6, w = idx & 63;
        tile[c][w] = xp[(size_t)c * HH * WW + w];
    }
    __syncthreads();
    __half* op = xth + ((size_t)(b * HH + y) * WW) * 64;
    #pragma unroll
    for (int k = 0; k < 16; ++k) {
        int idx = threadIdx.x + (k << 8);
        int w = idx >> 6, c = idx & 63;
        op[(size_t)w * 64 + c] = __float2half(tile[c][w]);
    }
}

// pointwise rows: lane = pixel (64), o0 wave-uniform -> scalar weight loads
template<int RPW>
__device__ inline void pw_acc(const float* __restrict__ P, int base, int lane, int o0, int R,
                              const float* __restrict__ W, const float* __restrict__ Bv,
                              float* acc) {
    int oc[RPW];
    #pragma unroll
    for (int r = 0; r < RPW; ++r) { oc[r] = min(o0 + r, R - 1); acc[r] = Bv[oc[r]]; }
    #pragma unroll 8
    for (int k = 0; k < 64; ++k) {
        float v = P[base + k * 65 + lane];
        #pragma unroll
        for (int r = 0; r < RPW; ++r) acc[r] = fmaf(W[oc[r] * 64 + k], v, acc[r]);
    }
}

// ---------------- fused main: 1 block (16 waves, 1024 thr) per image row ----------------
__global__ __launch_bounds__(1024, 4) void crossd_main(
    const __half* __restrict__ xth, const float* __restrict__ x,
    const float* __restrict__ p_n,
    const float* __restrict__ dwf_w, const float* __restrict__ dwf_b,
    const float* __restrict__ pwf_w, const float* __restrict__ pwf_b,
    const float* __restrict__ dwc_w, const float* __restrict__ dwc_b,
    const float* __restrict__ pwc_w, const float* __restrict__ pwc_b,
    const float* __restrict__ dwm_w, const float* __restrict__ dwm_b,
    const float* __restrict__ pwm_w, const float* __restrict__ pwm_b,
    const float* __restrict__ pc_w, const float* __restrict__ pc_b,
    const float* __restrict__ w1, const float* __restrict__ b1,
    const float* __restrict__ w2, const float* __restrict__ b2,
    float* __restrict__ out)
{
    __shared__ float P[POOLW];
    uint32_t* PU = reinterpret_cast<uint32_t*>(P);
    __half*   PH = reinterpret_cast<__half*>(P);
    const int tid  = threadIdx.x;
    const int lane = tid & 63;
    const int wv   = __builtin_amdgcn_readfirstlane(tid >> 6);   // 0..15
    const int b = blockIdx.x >> 6, y = blockIdx.x & 63;
    const int ry0 = min(max(y - 1, 0), 59);                      // window rows ry0..ry0+4
    const __half* xbh = xth + (size_t)b * (HH * WW * 64);
    const uint2* xb2 = reinterpret_cast<const uint2*>(xbh);

    // ---- phase 0: stage 5-row fp16 window into LDS (coalesced, conflict-free) ----
    {
        const int px = tid >> 4, c4v = tid & 15;
        uint2* WINu = reinterpret_cast<uint2*>(P);
        #pragma unroll
        for (int j = 0; j < 5; ++j) {
            int ry = ry0 + j;
            WINu[(j * 64 + px) * 16 + c4v] = xb2[((ry << 6) + px) * 16 + c4v];
        }
    }
    __syncthreads();   // B0

    // ---- depthwise 3x3 from LDS window (3 branches share reads); wave=4px, lane=ch ----
    float tc_r[4], tm_r[4];
    {
        const int c = lane;
        float wf9[9], wc9[9], wm9[9];
        #pragma unroll
        for (int k9 = 0; k9 < 9; ++k9) {
            wf9[k9] = dwf_w[c * 9 + k9];
            wc9[k9] = dwc_w[c * 9 + k9];
            wm9[k9] = dwm_w[c * 9 + k9];
        }
        const float bf = dwf_b[c], bc = dwc_b[c], bm = dwm_b[c];
        #pragma unroll
        for (int i = 0; i < 4; ++i) {
            const int px = wv * 4 + i;
            float af = bf, ac = bc, am = bm;
            #pragma unroll
            for (int dy = 0; dy < 3; ++dy) {
                int yy = y + dy - 1;
                if (yy < 0 || yy >= HH) continue;
                int j = yy - ry0;          // always in [0,4] (see ry0 clamp)
                #pragma unroll
                for (int dx = 0; dx < 3; ++dx) {
                    int xx = px + dx - 1;
                    if (xx < 0 || xx >= WW) continue;
                    float v = __half2float(PH[(j * 64 + xx) * 64 + c]);
                    int k = dy * 3 + dx;
                    af = fmaf(v, wf9[k], af);
                    ac = fmaf(v, wc9[k], ac);
                    am = fmaf(v, wm9[k], am);
                }
            }
            P[TAW + c * 65 + px] = af;
            tc_r[i] = ac; tm_r[i] = am;
        }
    }
    __syncthreads();   // B1

    // ---- f-branch pointwise (32 rows -> ox of taps 0..31) ----
    {
        float acc[2];
        pw_acc<2>(P, TAW, lane, wv * 2, 32, pwf_w, pwf_b, acc);
        __syncthreads();   // B2: TA reads done before t_c overwrite
        #pragma unroll
        for (int r = 0; r < 2; ++r) {
            int o = wv * 2 + r;
            P[SLOTW + (o * 64 + lane) * 4 + 0] = acc[r];
        }
        #pragma unroll
        for (int i = 0; i < 4; ++i) P[TAW + lane * 65 + wv * 4 + i] = tc_r[i];
    }
    __syncthreads();   // B3

    // ---- c-branch pointwise (72 rows -> ox taps 32..51, oy taps 0..51) ----
    {
        float acc[5];
        pw_acc<5>(P, TAW, lane, wv * 5, 72, pwc_w, pwc_b, acc);
        __syncthreads();   // B4: TA reads done before t_m overwrite
        #pragma unroll
        for (int r = 0; r < 5; ++r) {
            int rr = wv * 5 + r;
            if (rr < 72) {
                int og = 32 + rr;
                int e = (og < 52) ? (og * 64 + lane) * 4
                                  : ((og - 52) * 64 + lane) * 4 + 1;
                P[SLOTW + e] = acc[r];
            }
        }
        #pragma unroll
        for (int i = 0; i < 4; ++i) P[TAW + lane * 65 + wv * 4 + i] = tm_r[i];
    }
    __syncthreads();   // B5

    // ---- m-branch pointwise (53 rows -> score buffer SB, stride 67) ----
    {
        float acc[4];
        pw_acc<4>(P, TAW, lane, wv * 4, 53, pwm_w, pwm_b, acc);
        #pragma unroll
        for (int r = 0; r < 4; ++r) {
            int o = wv * 4 + r;
            if (o < 53) P[SBW + o * 67 + lane] = acc[r];
        }
    }
    __syncthreads();   // B6

    // ---- gated softmax over 52 scores (in-place in SB): lane = n, wave owns 4 px ----
    #pragma unroll
    for (int i = 0; i < 4; ++i) {
        const int px = wv * 4 + i;
        const float sp = P[SBW + 52 * 67 + px];
        float z = -1e30f;
        if (lane < 52) {
            float s  = P[SBW + lane * 67 + px];
            float sg = 1.0f / (1.0f + __expf(-(s - sp) * 10.0f));
            z = s + __logf(sg + 1e-10f);
        }
        float mx = z;
        #pragma unroll
        for (int d = 32; d >= 1; d >>= 1) mx = fmaxf(mx, __shfl_xor(mx, d));
        float e = (lane < 52) ? __expf(z - mx) : 0.0f;
        float sm = e;
        #pragma unroll
        for (int d = 32; d >= 1; d >>= 1) sm += __shfl_xor(sm, d);
        if (lane < 52) P[SBW + lane * 67 + px] = e / sm;
    }
    __syncthreads();   // B7

    // ---- coordpack: rewrite each SLOT entry as {4 u16 LDS offsets, 4 half weights} ----
    {
        const int ppx = tid & 63;
        const int g   = tid >> 6;              // wave-uniform n group
        for (int n = g; n < 52; n += 16) {
            const int e4 = SLOTW + (n * 64 + ppx) * 4;
            float sx = (float)ppx + p_n[n]      + P[e4 + 0];
            float sy = (float)y   + p_n[52 + n] + P[e4 + 1];
            float mo = P[SBW + n * 67 + ppx];
            float x0f = floorf(sx), y0f = floorf(sy);
            float wx1 = sx - x0f, wy1 = sy - y0f;
            float wx0 = 1.0f - wx1, wy0 = 1.0f - wy1;
            int x0 = (int)x0f, y0 = (int)y0f;
            int xi0 = min(max(x0, 0), 63), xi1 = min(max(x0 + 1, 0), 63);
            int yi0 = min(max(y0, 0), 63), yi1 = min(max(y0 + 1, 0), 63);
            bool vx0 = (x0 >= 0)  & (x0 <= 63);
            bool vx1 = (x0 >= -1) & (x0 <= 62);
            bool vy0 = (y0 >= 0)  & (y0 <= 63);
            bool vy1 = (y0 >= -1) & (y0 <= 62);
            float m00 = (vy0 & vx0) ? mo * wy0 * wx0 : 0.0f;
            float m01 = (vy0 & vx1) ? mo * wy0 * wx1 : 0.0f;
            float m10 = (vy1 & vx0) ? mo * wy1 * wx0 : 0.0f;
            float m11 = (vy1 & vx1) ? mo * wy1 * wx1 : 0.0f;
            int j0 = yi0 - ry0, j1 = yi1 - ry0;
            uint32_t w0, w1;
            if ((j0 >= 0) & (j1 <= 4)) {       // in-window: pack LDS byte offsets
                w0 = (uint32_t)((j0 * 64 + xi0) * 128) | ((uint32_t)((j0 * 64 + xi1) * 128) << 16);
                w1 = (uint32_t)((j1 * 64 + xi0) * 128) | ((uint32_t)((j1 * 64 + xi1) * 128) << 16);
            } else {                            // rare fallback: global addresses
                w0 = 0xFFFFFFFFu;
                w1 = (uint32_t)((yi0 << 6) | xi0) | ((uint32_t)((yi1 << 6) | xi1) << 16);
            }
            __half2 hA = __floats2half2_rn(m00, m01);
            __half2 hB = __floats2half2_rn(m10, m11);
            uint4 pkw;
            pkw.x = w0; pkw.y = w1;
            pkw.z = *reinterpret_cast<uint32_t*>(&hA);
            pkw.w = *reinterpret_cast<uint32_t*>(&hB);
            *reinterpret_cast<uint4*>(&PU[e4]) = pkw;
        }
    }
    __syncthreads();   // B8

    // ---- 52-tap gather from LDS window; lane = (px_sub, ch_quad) ----
    {
        const int sub = lane >> 4;      // 0..3
        const int c4  = lane & 15;      // channel quad
        const int spx = wv * 4 + sub;
        const int c4b = c4 * 8;         // byte offset of this lane's 4 channels
        const char* Pb = reinterpret_cast<const char*>(P);
        float4 agg = make_float4(0.f, 0.f, 0.f, 0.f);
        #pragma unroll 4
        for (int n = 0; n < 52; ++n) {
            const int e4 = SLOTW + (n * 64 + spx) * 4;
            uint4 pk = *reinterpret_cast<const uint4*>(&PU[e4]);
            uint2 v00, v01, v10, v11;
            if (pk.x != 0xFFFFFFFFu) {
                v00 = *reinterpret_cast<const uint2*>(Pb + (pk.x & 0xFFFFu) + c4b);
                v01 = *reinterpret_cast<const uint2*>(Pb + (pk.x >> 16)     + c4b);
                v10 = *reinterpret_cast<const uint2*>(Pb + (pk.y & 0xFFFFu) + c4b);
                v11 = *reinterpret_cast<const uint2*>(Pb + (pk.y >> 16)     + c4b);
            } else {
                uint32_t a00 = pk.y & 0xFFFFu, a11 = pk.y >> 16;
                uint32_t a01 = (a00 & ~63u) | (a11 & 63u);
                uint32_t a10 = (a11 & ~63u) | (a00 & 63u);
                v00 = xb2[(a00 << 4) + c4];
                v01 = xb2[(a01 << 4) + c4];
                v10 = xb2[(a10 << 4) + c4];
                v11 = xb2[(a11 << 4) + c4];
            }
            __half2 hA = *reinterpret_cast<const __half2*>(&pk.z);
            __half2 hB = *reinterpret_cast<const __half2*>(&pk.w);
            float m00 = __low2float(hA), m01 = __high2float(hA);
            float m10 = __low2float(hB), m11 = __high2float(hB);
            #define ACC4(u, m) { \
                __half2 hlo = *reinterpret_cast<const __half2*>(&u.x); \
                __half2 hhi = *reinterpret_cast<const __half2*>(&u.y); \
                float2 flo = __half22float2(hlo), fhi = __half22float2(hhi); \
                agg.x = fmaf(m, flo.x, agg.x); agg.y = fmaf(m, flo.y, agg.y); \
                agg.z = fmaf(m, fhi.x, agg.z); agg.w = fmaf(m, fhi.y, agg.w); }
            ACC4(v00, m00); ACC4(v01, m01); ACC4(v10, m10); ACC4(v11, m11);
            #undef ACC4
        }
        // agg transposed [c][px] into TA (last TA reader was m-branch, pre-B6)
        P[TAW + (c4 * 4 + 0) * 65 + spx] = agg.x;
        P[TAW + (c4 * 4 + 1) * 65 + spx] = agg.y;
        P[TAW + (c4 * 4 + 2) * 65 + spx] = agg.z;
        P[TAW + (c4 * 4 + 3) * 65 + spx] = agg.w;
    }
    __syncthreads();   // B9

    // ---- pc 1x1: TA -> TB (= SLOT region, dead after gather) ----
    {
        float acc[4];
        pw_acc<4>(P, TAW, lane, wv * 4, 64, pc_w, pc_b, acc);
        #pragma unroll
        for (int r = 0; r < 4; ++r) P[SLOTW + (wv * 4 + r) * 65 + lane] = acc[r];
    }
    __syncthreads();   // B10

    // ---- mlp1 (relu): TB -> TA ----
    {
        const int o0 = wv * 4;
        float acc[4];
        pw_acc<4>(P, SLOTW, lane, o0, 64, w1, b1, acc);
        #pragma unroll
        for (int r = 0; r < 4; ++r) P[TAW + (o0 + r) * 65 + lane] = fmaxf(acc[r], 0.0f);
    }
    __syncthreads();   // B11

    // ---- mlp2 + residual + coalesced NCHW store ----
    {
        const int o0 = wv * 4;
        float acc[4];
        pw_acc<4>(P, TAW, lane, o0, 64, w2, b2, acc);
        #pragma unroll
        for (int r = 0; r < 4; ++r) {
            int o = o0 + r;
            size_t idx = (((size_t)b * 64 + o) * 64 + y) * 64 + lane;
            out[idx] = acc[r] + x[idx];
        }
    }
}

extern "C" void kernel_launch(void* const* d_in, const int* in_sizes, int n_in,
                              void* d_out, int out_size, void* d_ws, size_t ws_size,
                              hipStream_t stream) {
    const float* x     = (const float*)d_in[0];
    const float* p_n   = (const float*)d_in[1];
    const float* dwf_w = (const float*)d_in[2];
    const float* dwf_b = (const float*)d_in[3];
    const float* pwf_w = (const float*)d_in[4];
    const float* pwf_b = (const float*)d_in[5];
    const float* dwc_w = (const float*)d_in[6];
    const float* dwc_b = (const float*)d_in[7];
    const float* pwc_w = (const float*)d_in[8];
    const float* pwc_b = (const float*)d_in[9];
    const float* dwm_w = (const float*)d_in[10];
    const float* dwm_b = (const float*)d_in[11];
    const float* pwm_w = (const float*)d_in[12];
    const float* pwm_b = (const float*)d_in[13];
    const float* pc_w  = (const float*)d_in[14];
    const float* pc_b  = (const float*)d_in[15];
    const float* w1    = (const float*)d_in[16];
    const float* b1    = (const float*)d_in[17];
    const float* w2    = (const float*)d_in[18];
    const float* b2    = (const float*)d_in[19];

    __half* xth = (__half*)d_ws;      // 2 MB NHWC fp16 copy of x
    float* outp = (float*)d_out;

    hipLaunchKernelGGL(transpose_half, dim3(BB * HH), dim3(256), 0, stream, x, xth);
    hipLaunchKernelGGL(crossd_main, dim3(BB * HH), dim3(1024), 0, stream,
                       xth, x, p_n,
                       dwf_w, dwf_b, pwf_w, pwf_b,
                       dwc_w, dwc_b, pwc_w, pwc_b,
                       dwm_w, dwm_b, pwm_w, pwm_b,
                       pc_w, pc_b, w1, b1, w2, b2, outp);
}